// Round 2
// baseline (125.499 us; speedup 1.0000x reference)
//
#include <hip/hip_runtime.h>

#define NN 4096
#define BB 8

// Partial-product kernel, v2: no LDS. pred[b,s] is wave-uniform -> scalar
// loads; P loaded as float2 per thread (2 destination columns per thread).
// grid = (NN/512 d-tiles, S s-chunks), block = 256 threads.
__global__ void __launch_bounds__(256)
diff_partial_kernel(const float* __restrict__ pred,
                    const float* __restrict__ P,
                    float* __restrict__ partial,  // [S][BB][NN]
                    int C)                        // s-chunk length = NN/S
{
    const int d0 = (blockIdx.x * 256 + threadIdx.x) * 2;
    const int s0 = blockIdx.y * C;

    float2 acc[BB];
#pragma unroll
    for (int b = 0; b < BB; ++b) { acc[b].x = 1.0f; acc[b].y = 1.0f; }

    const float* Prow = P + (size_t)s0 * NN + d0;

    for (int c = 0; c < C; c += 4) {
        // 8 wave-uniform float4 loads -> s_load_dwordx4 (scalar pipe)
        float4 pr[BB];
#pragma unroll
        for (int b = 0; b < BB; ++b)
            pr[b] = *(const float4*)(pred + b * NN + s0 + c);

#pragma unroll
        for (int k = 0; k < 4; ++k) {
            const float2 pv = *(const float2*)(Prow + (size_t)k * NN);
            const float prk[BB] = { pr[0].x, pr[1].x, pr[2].x, pr[3].x,
                                    pr[4].x, pr[5].x, pr[6].x, pr[7].x };
            (void)prk;
#pragma unroll
            for (int b = 0; b < BB; ++b) {
                const float p = (k == 0) ? ((const float*)&pr[b])[0]
                              : (k == 1) ? ((const float*)&pr[b])[1]
                              : (k == 2) ? ((const float*)&pr[b])[2]
                                         : ((const float*)&pr[b])[3];
                acc[b].x *= fmaf(-p, pv.x, 1.0f);
                acc[b].y *= fmaf(-p, pv.y, 1.0f);
            }
        }
        Prow += (size_t)4 * NN;
    }

    const int chunk = blockIdx.y;
    float* out = partial + ((size_t)chunk * BB) * NN + d0;
#pragma unroll
    for (int b = 0; b < BB; ++b) {
        *(float2*)(out + (size_t)b * NN) = acc[b];
    }
}

// Combine kernel: pred_out[b,d] = 1 - prod over chunks of partial[chunk][b][d]
// float4-vectorized over the flat BB*NN index.
__global__ void __launch_bounds__(256)
diff_combine_kernel(const float* __restrict__ partial, int S,
                    float* __restrict__ pred_out)
{
    const int idx4 = (blockIdx.x * 256 + threadIdx.x) * 4;  // over BB*NN
    float4 acc = make_float4(1.0f, 1.0f, 1.0f, 1.0f);
    for (int ch = 0; ch < S; ++ch) {
        const float4 p = *(const float4*)(partial + (size_t)ch * BB * NN + idx4);
        acc.x *= p.x; acc.y *= p.y; acc.z *= p.z; acc.w *= p.w;
    }
    float4 r;
    r.x = 1.0f - acc.x; r.y = 1.0f - acc.y;
    r.z = 1.0f - acc.z; r.w = 1.0f - acc.w;
    *(float4*)(pred_out + idx4) = r;
}

extern "C" void kernel_launch(void* const* d_in, const int* in_sizes, int n_in,
                              void* d_out, int out_size, void* d_ws, size_t ws_size,
                              hipStream_t stream) {
    const float* preds = (const float*)d_in[0];
    // d_in[1] = seed_idx (unused, matches reference)
    const float* P     = (const float*)d_in[2];
    float* out = (float*)d_out;

    // ws layout: [pred ping buffer: BB*NN floats][partials: S*BB*NN floats]
    float* pred_ping = (float*)d_ws;
    float* partial   = pred_ping + (size_t)BB * NN;

    // largest S (<=64, power of 2) whose buffers fit in ws
    int S = 64;
    while (S > 1 && (size_t)(S + 1) * BB * NN * sizeof(float) > ws_size) S >>= 1;
    const int C = NN / S;

    dim3 pgrid(NN / 512, S);
    dim3 cgrid((BB * NN) / (256 * 4));

    const float* cur = preds;
    for (int it = 0; it < 4; ++it) {
        float* dst = (it & 1) ? out : pred_ping;  // it: 0->ping,1->out,2->ping,3->out
        diff_partial_kernel<<<pgrid, 256, 0, stream>>>(cur, P, partial, C);
        diff_combine_kernel<<<cgrid, 256, 0, stream>>>(partial, S, dst);
        cur = dst;
    }
}